// Round 1
// baseline (114.752 us; speedup 1.0000x reference)
//
#include <hip/hip_runtime.h>
#include <math.h>

#define NAG 64
#define ZD  512
#define DM  512

// ---------------------------------------------------------------------------
// Kernel A: batched per-agent GEMV for Q, K, V.
// One wave handles 4 consecutive rows (same agent, same matrix).
// Lane l holds z-fragments z[l*4..l*4+3] and z[256+l*4..+3]; each row is two
// coalesced float4 loads (1 KB per wave per instruction) + 8 FMA + reduce.
// ---------------------------------------------------------------------------
__global__ __launch_bounds__(256) void qkv_gemv_kernel(
    const float* __restrict__ z,
    const float* __restrict__ Wq,
    const float* __restrict__ Wk,
    const float* __restrict__ Wv,
    float* __restrict__ Q, float* __restrict__ K, float* __restrict__ V)
{
    const int wave = threadIdx.x >> 6;
    const int lane = threadIdx.x & 63;
    const int rowBase = blockIdx.x * 16 + wave * 4;   // in [0, 3*64*512)
    const int m   = rowBase >> 15;                    // which matrix (0,1,2)
    const int rem = rowBase & 32767;
    const int n   = rem >> 9;                         // agent
    const int d0  = rem & 511;                        // first output row

    const float* __restrict__ W = (m == 0) ? Wq : ((m == 1) ? Wk : Wv);
    float* __restrict__ O       = (m == 0) ? Q  : ((m == 1) ? K  : V);

    const float* zr = z + n * ZD;
    const float4 zA = *reinterpret_cast<const float4*>(zr + lane * 4);
    const float4 zB = *reinterpret_cast<const float4*>(zr + 256 + lane * 4);

    const float* Wbase = W + ((size_t)(n * DM + d0)) * ZD;
    float acc[4];
#pragma unroll
    for (int r = 0; r < 4; ++r) {
        const float* wr = Wbase + (size_t)r * ZD;
        const float4 a = *reinterpret_cast<const float4*>(wr + lane * 4);
        const float4 b = *reinterpret_cast<const float4*>(wr + 256 + lane * 4);
        acc[r] = a.x*zA.x + a.y*zA.y + a.z*zA.z + a.w*zA.w
               + b.x*zB.x + b.y*zB.y + b.z*zB.z + b.w*zB.w;
    }
#pragma unroll
    for (int r = 0; r < 4; ++r) {
        float v = acc[r];
#pragma unroll
        for (int off = 32; off > 0; off >>= 1) v += __shfl_down(v, off);
        if (lane == 0) O[n * DM + d0 + r] = v;
    }
}

// ---------------------------------------------------------------------------
// Kernel B: one block per receiver column j.
// S[i][j] = <K_i, Q_j>/sqrt(D), diag = -inf, softmax over i, then
// messages[j][d] = sum_i alpha[i] * V[i][d]  (coalesced over d).
// ---------------------------------------------------------------------------
__global__ __launch_bounds__(256) void attn_msg_kernel(
    const float* __restrict__ Q, const float* __restrict__ K,
    const float* __restrict__ V, float* __restrict__ out)
{
    __shared__ __align__(16) float Qs[DM];
    __shared__ float Sc[NAG];
    __shared__ float Al[NAG];
    const int j = blockIdx.x;
    const int t = threadIdx.x;

    Qs[t]       = Q[j * DM + t];
    Qs[t + 256] = Q[j * DM + t + 256];
    __syncthreads();

    // 4 threads per sender i; each does 128 of the 512-dot.
    const int i = t >> 2;
    const int c = t & 3;
    const float* Krow = K + i * DM + c * 128;
    const float* Qsub = Qs + c * 128;
    float p = 0.f;
#pragma unroll
    for (int k = 0; k < 32; ++k) {
        float4 kv = *reinterpret_cast<const float4*>(Krow + k * 4);
        float4 qv = *reinterpret_cast<const float4*>(Qsub + k * 4);
        p += kv.x*qv.x + kv.y*qv.y + kv.z*qv.z + kv.w*qv.w;
    }
    p += __shfl_xor(p, 1);
    p += __shfl_xor(p, 2);
    if (c == 0) {
        Sc[i] = (i == j) ? -INFINITY : p * 0.044194173824159216f; // 1/sqrt(512)
    }
    __syncthreads();

    // softmax over the 64-entry column, done by wave 0
    if (t < 64) {
        float s = Sc[t];
        float mx = s;
#pragma unroll
        for (int off = 32; off > 0; off >>= 1) mx = fmaxf(mx, __shfl_xor(mx, off));
        float e = expf(s - mx);           // expf(-inf - mx) = 0 masks the diagonal
        float sum = e;
#pragma unroll
        for (int off = 32; off > 0; off >>= 1) sum += __shfl_xor(sum, off);
        Al[t] = e / sum;
    }
    __syncthreads();

    // messages[j][d] = sum_i Al[i] * V[i][d]
#pragma unroll
    for (int dd = 0; dd < 2; ++dd) {
        const int d = t + dd * 256;
        float acc = 0.f;
        for (int i2 = 0; i2 < NAG; ++i2) acc += Al[i2] * V[i2 * DM + d];
        out[j * DM + d] = acc;
    }
}

// ---------------------------------------------------------------------------
// Kernel C: one block per agent n. hat[n][zp] = <V[n], Wi[zp]> + bi[zp];
// accumulate (hat - z)^2 over zp; write per-agent sum of squared errors.
// ---------------------------------------------------------------------------
__global__ __launch_bounds__(256) void infer_loss_kernel(
    const float* __restrict__ V, const float* __restrict__ Wi,
    const float* __restrict__ bi, const float* __restrict__ z,
    float* __restrict__ agent_partial)
{
    const int n    = blockIdx.x;
    const int wave = threadIdx.x >> 6;
    const int lane = threadIdx.x & 63;

    const float* vr = V + n * DM;
    const float4 vA = *reinterpret_cast<const float4*>(vr + lane * 4);
    const float4 vB = *reinterpret_cast<const float4*>(vr + 256 + lane * 4);

    float errsum = 0.f;
    for (int zp = wave; zp < ZD; zp += 4) {
        const float* wr = Wi + (size_t)zp * DM;
        const float4 a = *reinterpret_cast<const float4*>(wr + lane * 4);
        const float4 b = *reinterpret_cast<const float4*>(wr + 256 + lane * 4);
        float p = a.x*vA.x + a.y*vA.y + a.z*vA.z + a.w*vA.w
                + b.x*vB.x + b.y*vB.y + b.z*vB.z + b.w*vB.w;
#pragma unroll
        for (int off = 32; off > 0; off >>= 1) p += __shfl_down(p, off);
        if (lane == 0) {
            float e = p + bi[zp] - z[n * ZD + zp];
            errsum += e * e;
        }
    }
    __shared__ float wsum[4];
    if (lane == 0) wsum[wave] = errsum;
    __syncthreads();
    if (threadIdx.x == 0) {
        agent_partial[n] = wsum[0] + wsum[1] + wsum[2] + wsum[3];
    }
}

// ---------------------------------------------------------------------------
// Kernel D: fold the 64 per-agent partials into the scalar loss.
// ---------------------------------------------------------------------------
__global__ __launch_bounds__(64) void loss_reduce_kernel(
    const float* __restrict__ agent_partial, float* __restrict__ out)
{
    float v = agent_partial[threadIdx.x];
#pragma unroll
    for (int off = 32; off > 0; off >>= 1) v += __shfl_down(v, off);
    if (threadIdx.x == 0) out[NAG * DM] = v * (1.0f / (NAG * ZD));
}

extern "C" void kernel_launch(void* const* d_in, const int* in_sizes, int n_in,
                              void* d_out, int out_size, void* d_ws, size_t ws_size,
                              hipStream_t stream) {
    const float* z  = (const float*)d_in[0];
    const float* Wq = (const float*)d_in[1];
    const float* Wk = (const float*)d_in[2];
    const float* Wv = (const float*)d_in[3];
    const float* Wi = (const float*)d_in[4];
    const float* bi = (const float*)d_in[5];
    float* out = (float*)d_out;

    float* Q = (float*)d_ws;
    float* K = Q + NAG * DM;
    float* V = K + NAG * DM;
    float* partial = V + NAG * DM;

    // 3 matrices * 64 agents * 512 rows / 16 rows per block = 6144 blocks
    hipLaunchKernelGGL(qkv_gemv_kernel, dim3(6144), dim3(256), 0, stream,
                       z, Wq, Wk, Wv, Q, K, V);
    hipLaunchKernelGGL(attn_msg_kernel, dim3(NAG), dim3(256), 0, stream,
                       Q, K, V, out);
    hipLaunchKernelGGL(infer_loss_kernel, dim3(NAG), dim3(256), 0, stream,
                       V, Wi, bi, z, partial);
    hipLaunchKernelGGL(loss_reduce_kernel, dim3(1), dim3(64), 0, stream,
                       partial, out);
}

// Round 2
// 53.948 us; speedup vs baseline: 2.1271x; 2.1271x over previous
//
#include <hip/hip_runtime.h>
#include <math.h>

#define NAG 64
#define ZD  512
#define DM  512

// ---------------------------------------------------------------------------
// Kernel A: batched per-agent GEMV for Q, K, V.
// One wave handles 4 consecutive rows (same agent, same matrix).
// Lane l holds z-fragments z[l*4..l*4+3] and z[256+l*4..+3]; each row is two
// coalesced float4 loads (1 KB per wave per instruction) + 8 FMA + reduce.
// ---------------------------------------------------------------------------
__global__ __launch_bounds__(256) void qkv_gemv_kernel(
    const float* __restrict__ z,
    const float* __restrict__ Wq,
    const float* __restrict__ Wk,
    const float* __restrict__ Wv,
    float* __restrict__ Q, float* __restrict__ K, float* __restrict__ V)
{
    const int wave = threadIdx.x >> 6;
    const int lane = threadIdx.x & 63;
    const int rowBase = blockIdx.x * 16 + wave * 4;   // in [0, 3*64*512)
    const int m   = rowBase >> 15;                    // which matrix (0,1,2)
    const int rem = rowBase & 32767;
    const int n   = rem >> 9;                         // agent
    const int d0  = rem & 511;                        // first output row

    const float* __restrict__ W = (m == 0) ? Wq : ((m == 1) ? Wk : Wv);
    float* __restrict__ O       = (m == 0) ? Q  : ((m == 1) ? K  : V);

    const float* zr = z + n * ZD;
    const float4 zA = *reinterpret_cast<const float4*>(zr + lane * 4);
    const float4 zB = *reinterpret_cast<const float4*>(zr + 256 + lane * 4);

    const float* Wbase = W + ((size_t)(n * DM + d0)) * ZD;
    float acc[4];
#pragma unroll
    for (int r = 0; r < 4; ++r) {
        const float* wr = Wbase + (size_t)r * ZD;
        const float4 a = *reinterpret_cast<const float4*>(wr + lane * 4);
        const float4 b = *reinterpret_cast<const float4*>(wr + 256 + lane * 4);
        acc[r] = a.x*zA.x + a.y*zA.y + a.z*zA.z + a.w*zA.w
               + b.x*zB.x + b.y*zB.y + b.z*zB.z + b.w*zB.w;
    }
#pragma unroll
    for (int r = 0; r < 4; ++r) {
        float v = acc[r];
#pragma unroll
        for (int off = 32; off > 0; off >>= 1) v += __shfl_down(v, off);
        if (lane == 0) O[n * DM + d0 + r] = v;
    }
}

// ---------------------------------------------------------------------------
// Kernel B: one block per receiver column j.
// S[i][j] = <K_i, Q_j>/sqrt(D), diag = -inf, softmax over i, then
// messages[j][d] = sum_i alpha[i] * V[i][d]  (coalesced over d).
// ---------------------------------------------------------------------------
__global__ __launch_bounds__(256) void attn_msg_kernel(
    const float* __restrict__ Q, const float* __restrict__ K,
    const float* __restrict__ V, float* __restrict__ out)
{
    __shared__ __align__(16) float Qs[DM];
    __shared__ float Sc[NAG];
    __shared__ float Al[NAG];
    const int j = blockIdx.x;
    const int t = threadIdx.x;

    Qs[t]       = Q[j * DM + t];
    Qs[t + 256] = Q[j * DM + t + 256];
    __syncthreads();

    // 4 threads per sender i; each does 128 of the 512-dot.
    const int i = t >> 2;
    const int c = t & 3;
    const float* Krow = K + i * DM + c * 128;
    const float* Qsub = Qs + c * 128;
    float p = 0.f;
#pragma unroll
    for (int k = 0; k < 32; ++k) {
        float4 kv = *reinterpret_cast<const float4*>(Krow + k * 4);
        float4 qv = *reinterpret_cast<const float4*>(Qsub + k * 4);
        p += kv.x*qv.x + kv.y*qv.y + kv.z*qv.z + kv.w*qv.w;
    }
    p += __shfl_xor(p, 1);
    p += __shfl_xor(p, 2);
    if (c == 0) {
        Sc[i] = (i == j) ? -INFINITY : p * 0.044194173824159216f; // 1/sqrt(512)
    }
    __syncthreads();

    // softmax over the 64-entry column, done by wave 0
    if (t < 64) {
        float s = Sc[t];
        float mx = s;
#pragma unroll
        for (int off = 32; off > 0; off >>= 1) mx = fmaxf(mx, __shfl_xor(mx, off));
        float e = expf(s - mx);           // expf(-inf - mx) = 0 masks the diagonal
        float sum = e;
#pragma unroll
        for (int off = 32; off > 0; off >>= 1) sum += __shfl_xor(sum, off);
        Al[t] = e / sum;
    }
    __syncthreads();

    // messages[j][d] = sum_i Al[i] * V[i][d]
#pragma unroll
    for (int dd = 0; dd < 2; ++dd) {
        const int d = t + dd * 256;
        float acc = 0.f;
        for (int i2 = 0; i2 < NAG; ++i2) acc += Al[i2] * V[i2 * DM + d];
        out[j * DM + d] = acc;
    }
}

// ---------------------------------------------------------------------------
// Kernel C (rewritten for parallelism): one block per output-dim zp.
// hat[i][zp] = <V[i], Wi[zp]> + bi[zp]; block computes sum_i (hat-z)^2 for
// its zp and writes one partial. 512 blocks -> 2 blocks/CU, no serial chain.
// ---------------------------------------------------------------------------
__global__ __launch_bounds__(256) void infer_loss_kernel(
    const float* __restrict__ V, const float* __restrict__ Wi,
    const float* __restrict__ bi, const float* __restrict__ z,
    float* __restrict__ zp_partial)
{
    __shared__ __align__(16) float Ws[DM];
    __shared__ float wsum[4];
    const int zp = blockIdx.x;
    const int t  = threadIdx.x;

    const float* wr = Wi + (size_t)zp * DM;
    Ws[t]       = wr[t];
    Ws[t + 256] = wr[t + 256];
    __syncthreads();

    // 4 threads per agent i; each does 128 of the 512-dot V[i]·Wi[zp].
    const int i = t >> 2;
    const int c = t & 3;
    const float* Vrow = V + i * DM + c * 128;
    const float* Wsub = Ws + c * 128;
    float p = 0.f;
#pragma unroll
    for (int k = 0; k < 32; ++k) {
        float4 vv = *reinterpret_cast<const float4*>(Vrow + k * 4);
        float4 wv = *reinterpret_cast<const float4*>(Wsub + k * 4);
        p += vv.x*wv.x + vv.y*wv.y + vv.z*wv.z + vv.w*wv.w;
    }
    p += __shfl_xor(p, 1);
    p += __shfl_xor(p, 2);

    float e2 = 0.f;
    if (c == 0) {
        float e = p + bi[zp] - z[i * ZD + zp];
        e2 = e * e;
    }
    // full-wave reduce; non-c0 lanes contribute 0
#pragma unroll
    for (int off = 32; off > 0; off >>= 1) e2 += __shfl_down(e2, off);

    const int wave = t >> 6;
    const int lane = t & 63;
    if (lane == 0) wsum[wave] = e2;
    __syncthreads();
    if (t == 0) zp_partial[zp] = wsum[0] + wsum[1] + wsum[2] + wsum[3];
}

// ---------------------------------------------------------------------------
// Kernel D: fold the 512 per-zp partials into the scalar loss.
// ---------------------------------------------------------------------------
__global__ __launch_bounds__(64) void loss_reduce_kernel(
    const float* __restrict__ zp_partial, float* __restrict__ out)
{
    float v = 0.f;
#pragma unroll
    for (int k = 0; k < 8; ++k) v += zp_partial[threadIdx.x + k * 64];
#pragma unroll
    for (int off = 32; off > 0; off >>= 1) v += __shfl_down(v, off);
    if (threadIdx.x == 0) out[NAG * DM] = v * (1.0f / (NAG * ZD));
}

extern "C" void kernel_launch(void* const* d_in, const int* in_sizes, int n_in,
                              void* d_out, int out_size, void* d_ws, size_t ws_size,
                              hipStream_t stream) {
    const float* z  = (const float*)d_in[0];
    const float* Wq = (const float*)d_in[1];
    const float* Wk = (const float*)d_in[2];
    const float* Wv = (const float*)d_in[3];
    const float* Wi = (const float*)d_in[4];
    const float* bi = (const float*)d_in[5];
    float* out = (float*)d_out;

    float* Q = (float*)d_ws;
    float* K = Q + NAG * DM;
    float* V = K + NAG * DM;
    float* partial = V + NAG * DM;   // 512 floats

    // 3 matrices * 64 agents * 512 rows / 16 rows per block = 6144 blocks
    hipLaunchKernelGGL(qkv_gemv_kernel, dim3(6144), dim3(256), 0, stream,
                       z, Wq, Wk, Wv, Q, K, V);
    hipLaunchKernelGGL(attn_msg_kernel, dim3(NAG), dim3(256), 0, stream,
                       Q, K, V, out);
    hipLaunchKernelGGL(infer_loss_kernel, dim3(ZD), dim3(256), 0, stream,
                       V, Wi, bi, z, partial);
    hipLaunchKernelGGL(loss_reduce_kernel, dim3(1), dim3(64), 0, stream,
                       partial, out);
}

// Round 3
// 52.285 us; speedup vs baseline: 2.1947x; 1.0318x over previous
//
#include <hip/hip_runtime.h>
#include <math.h>

#define NAG 64
#define ZD  512
#define DM  512

// ---------------------------------------------------------------------------
// Kernel A: batched per-agent GEMV for Q, K, V — persistent, pipelined.
// 2048 blocks x 4 waves; each wave owns 12 consecutive rows of the flattened
// [3*64*512] row space, processed as 3 groups of 4 rows with double-buffered
// register staging: group g+1's 10 float4 loads are issued before group g's
// FMAs/reduce, so loads stay in flight continuously (counted vmcnt).
// ---------------------------------------------------------------------------
struct GBuf {
    float4 w0, w1, w2, w3, w4, w5, w6, w7;  // 4 rows x 2 halves
    float4 zA, zB;                          // z fragments for this agent
    float* outp;                            // &O[n*DM + d0]
};

__device__ __forceinline__ void issue_group(
    int rowBase, int lane,
    const float* __restrict__ z,
    const float* __restrict__ Wq, const float* __restrict__ Wk,
    const float* __restrict__ Wv,
    float* __restrict__ Q, float* __restrict__ K, float* __restrict__ V,
    GBuf& b)
{
    const int m   = rowBase >> 15;          // which matrix
    const int rem = rowBase & 32767;
    const int n   = rem >> 9;               // agent
    const int d0  = rem & 511;              // first output row (multiple of 4)
    const float* __restrict__ W = (m == 0) ? Wq : ((m == 1) ? Wk : Wv);
    float* __restrict__ O       = (m == 0) ? Q  : ((m == 1) ? K  : V);

    const float* zr = z + n * ZD;
    b.zA = *reinterpret_cast<const float4*>(zr + lane * 4);
    b.zB = *reinterpret_cast<const float4*>(zr + 256 + lane * 4);

    const float* Wb = W + ((size_t)(n * DM + d0)) * ZD;
    b.w0 = *reinterpret_cast<const float4*>(Wb + lane * 4);
    b.w1 = *reinterpret_cast<const float4*>(Wb + 256 + lane * 4);
    b.w2 = *reinterpret_cast<const float4*>(Wb + ZD + lane * 4);
    b.w3 = *reinterpret_cast<const float4*>(Wb + ZD + 256 + lane * 4);
    b.w4 = *reinterpret_cast<const float4*>(Wb + 2 * ZD + lane * 4);
    b.w5 = *reinterpret_cast<const float4*>(Wb + 2 * ZD + 256 + lane * 4);
    b.w6 = *reinterpret_cast<const float4*>(Wb + 3 * ZD + lane * 4);
    b.w7 = *reinterpret_cast<const float4*>(Wb + 3 * ZD + 256 + lane * 4);
    b.outp = O + n * DM + d0;
}

__device__ __forceinline__ void compute_group(int lane, const GBuf& b)
{
    float a0 = b.w0.x*b.zA.x + b.w0.y*b.zA.y + b.w0.z*b.zA.z + b.w0.w*b.zA.w
             + b.w1.x*b.zB.x + b.w1.y*b.zB.y + b.w1.z*b.zB.z + b.w1.w*b.zB.w;
    float a1 = b.w2.x*b.zA.x + b.w2.y*b.zA.y + b.w2.z*b.zA.z + b.w2.w*b.zA.w
             + b.w3.x*b.zB.x + b.w3.y*b.zB.y + b.w3.z*b.zB.z + b.w3.w*b.zB.w;
    float a2 = b.w4.x*b.zA.x + b.w4.y*b.zA.y + b.w4.z*b.zA.z + b.w4.w*b.zA.w
             + b.w5.x*b.zB.x + b.w5.y*b.zB.y + b.w5.z*b.zB.z + b.w5.w*b.zB.w;
    float a3 = b.w6.x*b.zA.x + b.w6.y*b.zA.y + b.w6.z*b.zA.z + b.w6.w*b.zA.w
             + b.w7.x*b.zB.x + b.w7.y*b.zB.y + b.w7.z*b.zB.z + b.w7.w*b.zB.w;
#pragma unroll
    for (int off = 32; off > 0; off >>= 1) {   // 4 independent chains interleave
        a0 += __shfl_down(a0, off);
        a1 += __shfl_down(a1, off);
        a2 += __shfl_down(a2, off);
        a3 += __shfl_down(a3, off);
    }
    if (lane == 0) {
        b.outp[0] = a0; b.outp[1] = a1; b.outp[2] = a2; b.outp[3] = a3;
    }
}

__global__ __launch_bounds__(256) void qkv_gemv_kernel(
    const float* __restrict__ z,
    const float* __restrict__ Wq,
    const float* __restrict__ Wk,
    const float* __restrict__ Wv,
    float* __restrict__ Q, float* __restrict__ K, float* __restrict__ V)
{
    const int wave = threadIdx.x >> 6;
    const int lane = threadIdx.x & 63;
    const int gw = blockIdx.x * 4 + wave;     // 0..8191
    const int rb = gw * 12;                   // 12 rows per wave, 3 groups of 4

    GBuf A, B;
    issue_group(rb,     lane, z, Wq, Wk, Wv, Q, K, V, A);
    issue_group(rb + 4, lane, z, Wq, Wk, Wv, Q, K, V, B);
    compute_group(lane, A);                   // B's loads remain in flight
    issue_group(rb + 8, lane, z, Wq, Wk, Wv, Q, K, V, A);
    compute_group(lane, B);                   // A(g2) loads in flight
    compute_group(lane, A);
}

// ---------------------------------------------------------------------------
// Kernel B+C fused: blocks [0,64) do attention+messages for receiver j;
// blocks [64, 576) do the infer-loss partial for output-dim zp = blk-64.
// ---------------------------------------------------------------------------
__global__ __launch_bounds__(256) void attn_infer_kernel(
    const float* __restrict__ Q, const float* __restrict__ K,
    const float* __restrict__ V, const float* __restrict__ Wi,
    const float* __restrict__ bi, const float* __restrict__ z,
    float* __restrict__ out, float* __restrict__ zp_partial)
{
    __shared__ __align__(16) float sbuf[DM];
    __shared__ float Sc[NAG];
    __shared__ float Al[NAG];
    const int t = threadIdx.x;

    if (blockIdx.x < NAG) {
        // ---------------- attention + messages, receiver j ----------------
        const int j = blockIdx.x;
        sbuf[t]       = Q[j * DM + t];
        sbuf[t + 256] = Q[j * DM + t + 256];
        __syncthreads();

        const int i = t >> 2;                 // sender
        const int c = t & 3;
        const float* Krow = K + i * DM + c * 128;
        const float* Qsub = sbuf + c * 128;
        float p = 0.f;
#pragma unroll
        for (int k = 0; k < 32; ++k) {
            float4 kv = *reinterpret_cast<const float4*>(Krow + k * 4);
            float4 qv = *reinterpret_cast<const float4*>(Qsub + k * 4);
            p += kv.x*qv.x + kv.y*qv.y + kv.z*qv.z + kv.w*qv.w;
        }
        p += __shfl_xor(p, 1);
        p += __shfl_xor(p, 2);
        if (c == 0)
            Sc[i] = (i == j) ? -INFINITY : p * 0.044194173824159216f; // 1/sqrt(512)
        __syncthreads();

        if (t < 64) {
            float s = Sc[t];
            float mx = s;
#pragma unroll
            for (int off = 32; off > 0; off >>= 1) mx = fmaxf(mx, __shfl_xor(mx, off));
            float e = expf(s - mx);           // exp(-inf)=0 masks diagonal
            float sum = e;
#pragma unroll
            for (int off = 32; off > 0; off >>= 1) sum += __shfl_xor(sum, off);
            Al[t] = e / sum;
        }
        __syncthreads();

#pragma unroll
        for (int dd = 0; dd < 2; ++dd) {
            const int d = t + dd * 256;
            float acc = 0.f;
            for (int i2 = 0; i2 < NAG; ++i2) acc += Al[i2] * V[i2 * DM + d];
            out[j * DM + d] = acc;
        }
    } else {
        // ---------------- infer loss partial for output-dim zp ----------------
        const int zp = blockIdx.x - NAG;
        const float* wr = Wi + (size_t)zp * DM;
        sbuf[t]       = wr[t];
        sbuf[t + 256] = wr[t + 256];
        __syncthreads();

        const int i = t >> 2;                 // agent
        const int c = t & 3;
        const float* Vrow = V + i * DM + c * 128;
        const float* Wsub = sbuf + c * 128;
        float p = 0.f;
#pragma unroll
        for (int k = 0; k < 32; ++k) {
            float4 vv = *reinterpret_cast<const float4*>(Vrow + k * 4);
            float4 wv = *reinterpret_cast<const float4*>(Wsub + k * 4);
            p += vv.x*wv.x + vv.y*wv.y + vv.z*wv.z + vv.w*wv.w;
        }
        p += __shfl_xor(p, 1);
        p += __shfl_xor(p, 2);

        float e2 = 0.f;
        if (c == 0) {
            float e = p + bi[zp] - z[i * ZD + zp];
            e2 = e * e;
        }
#pragma unroll
        for (int off = 32; off > 0; off >>= 1) e2 += __shfl_down(e2, off);

        const int wv2 = t >> 6;
        const int ln  = t & 63;
        if (ln == 0) Sc[wv2] = e2;            // reuse small LDS array
        __syncthreads();
        if (t == 0) zp_partial[zp] = Sc[0] + Sc[1] + Sc[2] + Sc[3];
    }
}

// ---------------------------------------------------------------------------
// Kernel D: fold the 512 per-zp partials into the scalar loss.
// ---------------------------------------------------------------------------
__global__ __launch_bounds__(64) void loss_reduce_kernel(
    const float* __restrict__ zp_partial, float* __restrict__ out)
{
    float v = 0.f;
#pragma unroll
    for (int k = 0; k < 8; ++k) v += zp_partial[threadIdx.x + k * 64];
#pragma unroll
    for (int off = 32; off > 0; off >>= 1) v += __shfl_down(v, off);
    if (threadIdx.x == 0) out[NAG * DM] = v * (1.0f / (NAG * ZD));
}

extern "C" void kernel_launch(void* const* d_in, const int* in_sizes, int n_in,
                              void* d_out, int out_size, void* d_ws, size_t ws_size,
                              hipStream_t stream) {
    const float* z  = (const float*)d_in[0];
    const float* Wq = (const float*)d_in[1];
    const float* Wk = (const float*)d_in[2];
    const float* Wv = (const float*)d_in[3];
    const float* Wi = (const float*)d_in[4];
    const float* bi = (const float*)d_in[5];
    float* out = (float*)d_out;

    float* Q = (float*)d_ws;
    float* K = Q + NAG * DM;
    float* V = K + NAG * DM;
    float* partial = V + NAG * DM;   // 512 floats

    // 3*64*512 rows / (4 waves * 12 rows) = 2048 blocks (8 per CU), persistent
    hipLaunchKernelGGL(qkv_gemv_kernel, dim3(2048), dim3(256), 0, stream,
                       z, Wq, Wk, Wv, Q, K, V);
    hipLaunchKernelGGL(attn_infer_kernel, dim3(NAG + ZD), dim3(256), 0, stream,
                       Q, K, V, Wi, bi, z, out, partial);
    hipLaunchKernelGGL(loss_reduce_kernel, dim3(1), dim3(64), 0, stream,
                       partial, out);
}

// Round 4
// 51.004 us; speedup vs baseline: 2.2499x; 1.0251x over previous
//
#include <hip/hip_runtime.h>
#include <math.h>

#define NAG 64
#define ZD  512
#define DM  512
#define NG  6   // groups of 4 rows per wave: 24576 groups / 4096 waves

// ---------------------------------------------------------------------------
// Kernel A: batched per-agent GEMV for Q, K, V — explicit register prefetch.
// 1024 blocks x 4 waves; each wave owns 6 groups of 4 consecutive rows of the
// flattened [3*64*512] row space. Iteration it issues group it+1's 10 float4
// loads into PLAIN NAMED registers before computing group it, forcing a
// counted vmcnt (one group always in flight).
// ---------------------------------------------------------------------------
__device__ __forceinline__ void addr_group(
    int g, const float* __restrict__ z,
    const float* __restrict__ Wq, const float* __restrict__ Wk,
    const float* __restrict__ Wv,
    float* __restrict__ Q, float* __restrict__ K, float* __restrict__ V,
    const float*& wb, const float*& zr, float*& op)
{
    const int rowBase = g << 2;
    const int m   = rowBase >> 15;          // matrix select
    const int rem = rowBase & 32767;
    const int n   = rem >> 9;               // agent
    const int d0  = rem & 511;              // first output row (multiple of 4)
    const float* __restrict__ W = (m == 0) ? Wq : ((m == 1) ? Wk : Wv);
    float* __restrict__ O       = (m == 0) ? Q  : ((m == 1) ? K  : V);
    wb = W + ((size_t)(n * DM + d0)) * ZD;
    zr = z + n * ZD;
    op = O + n * DM + d0;
}

#define LDW(dst, base, r, h) \
    dst = *reinterpret_cast<const float4*>((base) + (r) * ZD + (h) * 256 + lane * 4)

__device__ __forceinline__ float dot8(float4 wa, float4 wb, float4 za, float4 zb)
{
    return wa.x*za.x + wa.y*za.y + wa.z*za.z + wa.w*za.w
         + wb.x*zb.x + wb.y*zb.y + wb.z*zb.z + wb.w*zb.w;
}

__device__ __forceinline__ void compute4(
    int lane,
    float4 w0, float4 w1, float4 w2, float4 w3,
    float4 w4, float4 w5, float4 w6, float4 w7,
    float4 za, float4 zb, float* op)
{
    float a0 = dot8(w0, w1, za, zb);
    float a1 = dot8(w2, w3, za, zb);
    float a2 = dot8(w4, w5, za, zb);
    float a3 = dot8(w6, w7, za, zb);
#pragma unroll
    for (int off = 32; off > 0; off >>= 1) {   // 4 independent chains interleave
        a0 += __shfl_down(a0, off);
        a1 += __shfl_down(a1, off);
        a2 += __shfl_down(a2, off);
        a3 += __shfl_down(a3, off);
    }
    if (lane == 0)
        *reinterpret_cast<float4*>(op) = make_float4(a0, a1, a2, a3);
}

__global__ __launch_bounds__(256) void qkv_gemv_kernel(
    const float* __restrict__ z,
    const float* __restrict__ Wq,
    const float* __restrict__ Wk,
    const float* __restrict__ Wv,
    float* __restrict__ Q, float* __restrict__ K, float* __restrict__ V)
{
    const int wave = threadIdx.x >> 6;
    const int lane = threadIdx.x & 63;
    const int gw = blockIdx.x * 4 + wave;     // 0..4095
    const int g0 = gw * NG;

    const float *cwb, *czr; float *cop;
    addr_group(g0, z, Wq, Wk, Wv, Q, K, V, cwb, czr, cop);
    float4 c0, c1, c2, c3, c4, c5, c6, c7, cza, czb;
    LDW(c0, cwb, 0, 0); LDW(c1, cwb, 0, 1);
    LDW(c2, cwb, 1, 0); LDW(c3, cwb, 1, 1);
    LDW(c4, cwb, 2, 0); LDW(c5, cwb, 2, 1);
    LDW(c6, cwb, 3, 0); LDW(c7, cwb, 3, 1);
    cza = *reinterpret_cast<const float4*>(czr + lane * 4);
    czb = *reinterpret_cast<const float4*>(czr + 256 + lane * 4);

#pragma unroll
    for (int it = 0; it < NG; ++it) {
        float4 n0, n1, n2, n3, n4, n5, n6, n7, nza, nzb;
        const float *nwb, *nzr; float *nop;
        if (it + 1 < NG) {
            addr_group(g0 + it + 1, z, Wq, Wk, Wv, Q, K, V, nwb, nzr, nop);
            LDW(n0, nwb, 0, 0); LDW(n1, nwb, 0, 1);
            LDW(n2, nwb, 1, 0); LDW(n3, nwb, 1, 1);
            LDW(n4, nwb, 2, 0); LDW(n5, nwb, 2, 1);
            LDW(n6, nwb, 3, 0); LDW(n7, nwb, 3, 1);
            nza = *reinterpret_cast<const float4*>(nzr + lane * 4);
            nzb = *reinterpret_cast<const float4*>(nzr + 256 + lane * 4);
        }
        compute4(lane, c0, c1, c2, c3, c4, c5, c6, c7, cza, czb, cop);
        if (it + 1 < NG) {
            c0 = n0; c1 = n1; c2 = n2; c3 = n3;
            c4 = n4; c5 = n5; c6 = n6; c7 = n7;
            cza = nza; czb = nzb; cop = nop;
        }
    }
}

// ---------------------------------------------------------------------------
// Kernel B+C fused: blocks [0,64) do attention+messages for receiver j;
// blocks [64, 576) do the infer-loss partial for output-dim zp = blk-64.
// ---------------------------------------------------------------------------
__global__ __launch_bounds__(256) void attn_infer_kernel(
    const float* __restrict__ Q, const float* __restrict__ K,
    const float* __restrict__ V, const float* __restrict__ Wi,
    const float* __restrict__ bi, const float* __restrict__ z,
    float* __restrict__ out, float* __restrict__ zp_partial)
{
    __shared__ __align__(16) float sbuf[DM];
    __shared__ float Sc[NAG];
    __shared__ float Al[NAG];
    const int t = threadIdx.x;

    if (blockIdx.x < NAG) {
        // ---------------- attention + messages, receiver j ----------------
        const int j = blockIdx.x;
        sbuf[t]       = Q[j * DM + t];
        sbuf[t + 256] = Q[j * DM + t + 256];
        __syncthreads();

        const int i = t >> 2;                 // sender
        const int c = t & 3;
        const float* Krow = K + i * DM + c * 128;
        const float* Qsub = sbuf + c * 128;
        float p = 0.f;
#pragma unroll
        for (int k = 0; k < 32; ++k) {
            float4 kv = *reinterpret_cast<const float4*>(Krow + k * 4);
            float4 qv = *reinterpret_cast<const float4*>(Qsub + k * 4);
            p += kv.x*qv.x + kv.y*qv.y + kv.z*qv.z + kv.w*qv.w;
        }
        p += __shfl_xor(p, 1);
        p += __shfl_xor(p, 2);
        if (c == 0)
            Sc[i] = (i == j) ? -INFINITY : p * 0.044194173824159216f; // 1/sqrt(512)
        __syncthreads();

        if (t < 64) {
            float s = Sc[t];
            float mx = s;
#pragma unroll
            for (int off = 32; off > 0; off >>= 1) mx = fmaxf(mx, __shfl_xor(mx, off));
            float e = expf(s - mx);           // exp(-inf)=0 masks diagonal
            float sum = e;
#pragma unroll
            for (int off = 32; off > 0; off >>= 1) sum += __shfl_xor(sum, off);
            Al[t] = e / sum;
        }
        __syncthreads();

#pragma unroll
        for (int dd = 0; dd < 2; ++dd) {
            const int d = t + dd * 256;
            float acc = 0.f;
            for (int i2 = 0; i2 < NAG; ++i2) acc += Al[i2] * V[i2 * DM + d];
            out[j * DM + d] = acc;
        }
    } else {
        // ---------------- infer loss partial for output-dim zp ----------------
        const int zp = blockIdx.x - NAG;
        const float* wr = Wi + (size_t)zp * DM;
        sbuf[t]       = wr[t];
        sbuf[t + 256] = wr[t + 256];
        __syncthreads();

        const int i = t >> 2;                 // agent
        const int c = t & 3;
        const float* Vrow = V + i * DM + c * 128;
        const float* Wsub = sbuf + c * 128;
        float p = 0.f;
#pragma unroll
        for (int k = 0; k < 32; ++k) {
            float4 vv = *reinterpret_cast<const float4*>(Vrow + k * 4);
            float4 wv = *reinterpret_cast<const float4*>(Wsub + k * 4);
            p += vv.x*wv.x + vv.y*wv.y + vv.z*wv.z + vv.w*wv.w;
        }
        p += __shfl_xor(p, 1);
        p += __shfl_xor(p, 2);

        float e2 = 0.f;
        if (c == 0) {
            float e = p + bi[zp] - z[i * ZD + zp];
            e2 = e * e;
        }
#pragma unroll
        for (int off = 32; off > 0; off >>= 1) e2 += __shfl_down(e2, off);

        const int wv2 = t >> 6;
        const int ln  = t & 63;
        if (ln == 0) Sc[wv2] = e2;            // reuse small LDS array
        __syncthreads();
        if (t == 0) zp_partial[zp] = Sc[0] + Sc[1] + Sc[2] + Sc[3];
    }
}

// ---------------------------------------------------------------------------
// Kernel D: fold the 512 per-zp partials into the scalar loss.
// ---------------------------------------------------------------------------
__global__ __launch_bounds__(64) void loss_reduce_kernel(
    const float* __restrict__ zp_partial, float* __restrict__ out)
{
    float v = 0.f;
#pragma unroll
    for (int k = 0; k < 8; ++k) v += zp_partial[threadIdx.x + k * 64];
#pragma unroll
    for (int off = 32; off > 0; off >>= 1) v += __shfl_down(v, off);
    if (threadIdx.x == 0) out[NAG * DM] = v * (1.0f / (NAG * ZD));
}

extern "C" void kernel_launch(void* const* d_in, const int* in_sizes, int n_in,
                              void* d_out, int out_size, void* d_ws, size_t ws_size,
                              hipStream_t stream) {
    const float* z  = (const float*)d_in[0];
    const float* Wq = (const float*)d_in[1];
    const float* Wk = (const float*)d_in[2];
    const float* Wv = (const float*)d_in[3];
    const float* Wi = (const float*)d_in[4];
    const float* bi = (const float*)d_in[5];
    float* out = (float*)d_out;

    float* Q = (float*)d_ws;
    float* K = Q + NAG * DM;
    float* V = K + NAG * DM;
    float* partial = V + NAG * DM;   // 512 floats

    // 24576 groups / (4 waves * 6 groups) = 1024 blocks, persistent-ish
    hipLaunchKernelGGL(qkv_gemv_kernel, dim3(1024), dim3(256), 0, stream,
                       z, Wq, Wk, Wv, Q, K, V);
    hipLaunchKernelGGL(attn_infer_kernel, dim3(NAG + ZD), dim3(256), 0, stream,
                       Q, K, V, Wi, bi, z, out, partial);
    hipLaunchKernelGGL(loss_reduce_kernel, dim3(1), dim3(64), 0, stream,
                       partial, out);
}